// Round 19
// baseline (126.253 us; speedup 1.0000x reference)
//
#include <hip/hip_runtime.h>
#include <hip/hip_bf16.h>

#define N_NODES 20000
#define E_ORIG  160000
#define E_TOT   180000
#define HEADS   8
#define HID     256
#define F1      2048   // HEADS*HID
#define NEG     0.2f
#define MAXDEG  96
#define GBKS    32     // K steps for gemm2: 2048/64
#define BMG     80     // gemm2 M-tile: 20000/80 = 250 blocks = 1/CU exact

typedef __attribute__((ext_vector_type(8))) short  short8;
typedef __attribute__((ext_vector_type(4))) short  short4_;
typedef __attribute__((ext_vector_type(4))) float  f32x4;

__device__ inline float bf2f(ushort u){ union{unsigned u32; float f;} v; v.u32=((unsigned)u)<<16; return v.f; }
__device__ inline ushort f2bf(float f){
  union{float f; unsigned u;} v; v.f=f;
  unsigned lsb=(v.u>>16)&1u; v.u += 0x7fffu + lsb; return (ushort)(v.u>>16);
}

__device__ inline void gload16(const ushort* g, ushort* s){
  __builtin_amdgcn_global_load_lds((const __attribute__((address_space(1))) unsigned int*)g,
                                   (__attribute__((address_space(3))) unsigned int*)s, 16, 0, 0);
}

// ---------------- fused prelude: prep + dots1 + cnt-zero + W2 transpose + ws2/wd2 ----------------
// ws2[k] = W2[k,:]·att_s2, wd2[k] = W2[k,:]·att_d2  (factorized conv2 attention dots)
__global__ __launch_bounds__(256) void k_pre(const float* __restrict__ x, const float* __restrict__ W1,
    const float* __restrict__ as1, const float* __restrict__ ad1, const float* __restrict__ W2,
    const float* __restrict__ as2, const float* __restrict__ ad2,
    float* __restrict__ a_src1, float* __restrict__ a_dst1, ushort* __restrict__ W2bT,
    float* __restrict__ ws2, float* __restrict__ wd2, int* __restrict__ cnt){
  __shared__ float s_w[128];
  __shared__ ushort sh[256][65];
  int tid = threadIdx.x, bid = blockIdx.x;
  if (tid < 128){
    int t = tid & 63;
    int k = t>>3, i = t&7;
    float v = 0.f;
    if (i < 7){
      const float* wp = W1 + i*F1 + (k<<8);
      const float* ap = ((tid<64) ? as1 : ad1) + (k<<8);
      f32x4 a4 = {0,0,0,0};
      for (int c=0;c<256;c+=4)
        a4 += (*(const f32x4*)&wp[c]) * (*(const f32x4*)&ap[c]);
      v = a4[0]+a4[1]+a4[2]+a4[3];
    }
    s_w[tid] = v;
  }
  __syncthreads();
  {
    int nl = tid>>3, k = tid&7;
    int n = bid*32 + nl;
    if (n < N_NODES){
      float s=0.f, d=0.f;
      const float* ws = &s_w[k*8];
      const float* wd = &s_w[64+k*8];
#pragma unroll
      for (int i=0;i<7;i++){
        float xv = x[n*7+i];
        s += xv*ws[i]; d += xv*wd[i];
      }
      a_src1[n*8+k]=s; a_dst1[n*8+k]=d;
    }
  }
  if (bid >= 32 && bid < 111){
    int i = (bid-32)*256 + tid;
    if (i < N_NODES) cnt[i] = 0;
  }
  if (bid >= 111 && bid < 367){
    // 256 blocks x 8 rows: ws2/wd2 row-dots of W2
    int r = (bid-111)*8 + (tid>>5);
    int l32 = tid&31;
    float ps=0.f, pd=0.f;
#pragma unroll
    for (int it=0; it<8; it++){
      int j = l32 + it*32;
      float w = W2[(size_t)r*256 + j];
      ps += w*as2[j]; pd += w*ad2[j];
    }
#pragma unroll
    for (int off=16; off; off>>=1){ ps += __shfl_xor(ps,off); pd += __shfl_xor(pd,off); }
    if (l32==0){ ws2[r]=ps; wd2[r]=pd; }
  }
  if (bid < 32){
    int k0 = bid*64;
    for (int kk=0; kk<64; kk++) sh[tid][kk] = f2bf(W2[(size_t)(k0+kk)*256 + tid]);
    __syncthreads();
#pragma unroll
    for (int c8=0; c8<8; c8++){
      short8 v;
#pragma unroll
      for (int j=0;j<8;j++) v[j] = (short)sh[tid][c8*8+j];
      *(short8*)&W2bT[(size_t)tid*F1 + k0 + c8*8] = v;
    }
  }
}

// ---------------- bucketed scatter ----------------
__global__ void k_scat(const int* __restrict__ ei, int* __restrict__ cnt, int* __restrict__ bucket){
  int e = blockIdx.x*256 + threadIdx.x;
  if (e >= E_TOT) return;
  int s, d;
  if (e < E_ORIG){ s = ei[e]; d = ei[E_ORIG + e]; }
  else           { s = d = e - E_ORIG; }
  int pos = atomicAdd(&cnt[d], 1);
  if (pos < MAXDEG) bucket[d*MAXDEG + pos] = s;
}

// ---------------- fused conv1: softmax+agg -> LDS -> W1 apply + ELU -> x2 + conv2 att-dots ----------------
__global__ __launch_bounds__(512) void k_sa1(const int* __restrict__ cnt, const int* __restrict__ bucket,
    const float* __restrict__ a_src1, const float* __restrict__ a_dst1,
    const float* __restrict__ x, const float* __restrict__ W1, const float* __restrict__ b1,
    const float* __restrict__ ws2, const float* __restrict__ wd2,
    ushort* __restrict__ x2, float* __restrict__ a_src2, float* __restrict__ a_dst2){
  __shared__ float sxa[8][64];
  __shared__ float sred[8][8][2];
  int tid = threadIdx.x, wv = tid>>6, lane = tid&63;
  int n = blockIdx.x*8 + wv;
  {
    int k = lane>>3, i = lane&7;
    int ie = (i==7)?0:i;
    int base = n*MAXDEG;
    int deg  = cnt[n]; if (deg>MAXDEG) deg=MAXDEG;
    float ad = a_dst1[n*8+k];
    int src0 = (lane<deg)    ? bucket[base+lane]    : 0;
    int src1 = (lane+64<deg) ? bucket[base+lane+64] : 0;
    float denom = 0.f, acc = 0.f;
    int j = 0;
    for (; j+2<=deg; j+=2){
      int s0 = (j<64)   ? __shfl(src0,j)     : __shfl(src1,j-64);
      int s1 = (j+1<64) ? __shfl(src0,j+1)   : __shfl(src1,j-63);
      float A0 = a_src1[(size_t)s0*8+k] + ad;
      float A1 = a_src1[(size_t)s1*8+k] + ad;
      float X0 = x[(size_t)s0*7+ie];
      float X1 = x[(size_t)s1*7+ie];
      A0 = (A0>0.f)?A0:NEG*A0;  A1 = (A1>0.f)?A1:NEG*A1;
      float w0 = __expf(A0),   w1 = __expf(A1);
      denom += w0; acc += w0*X0;
      denom += w1; acc += w1*X1;
    }
    if (j<deg){
      int s0 = (j<64) ? __shfl(src0,j) : __shfl(src1,j-64);
      float A0 = a_src1[(size_t)s0*8+k] + ad;
      A0 = (A0>0.f)?A0:NEG*A0;
      float w0 = __expf(A0);
      denom += w0; acc += w0*x[(size_t)s0*7+ie];
    }
    sxa[wv][lane] = acc/denom;
  }
  __syncthreads();
  // phase 2: apply W1 + ELU -> x2, and factorized conv2 attention dots
  int kh = tid>>6, c4 = (tid&63)<<2;
  f32x4 w1r[7];
#pragma unroll
  for (int i=0;i<7;i++) w1r[i] = *(const f32x4*)(W1 + i*F1 + (kh<<8) + c4);
  f32x4 bb   = *(const f32x4*)(b1  + (kh<<8) + c4);
  f32x4 ws2v = *(const f32x4*)(ws2 + (kh<<8) + c4);
  f32x4 wd2v = *(const f32x4*)(wd2 + (kh<<8) + c4);
#pragma unroll
  for (int g=0; g<8; g++){
    int nn = blockIdx.x*8 + g;
    const float* xa = &sxa[g][kh<<3];
    f32x4 h = bb;
#pragma unroll
    for (int i=0;i<7;i++) h += xa[i]*w1r[i];
    short4_ o;
    float ps = 0.f, pd = 0.f;
#pragma unroll
    for (int j=0;j<4;j++){
      float v=h[j]; v=(v>0.f)?v:(__expf(v)-1.f);
      o[j]=(short)f2bf(v);
      ps += v*ws2v[j]; pd += v*wd2v[j];
    }
    *(short4_*)(x2 + (size_t)nn*F1 + (kh<<8) + c4) = o;
#pragma unroll
    for (int off=32; off; off>>=1){ ps += __shfl_xor(ps,off); pd += __shfl_xor(pd,off); }
    if (lane==0){ sred[g][wv][0]=ps; sred[g][wv][1]=pd; }
  }
  __syncthreads();
  if (tid < 16){
    int g = tid>>1, sel = tid&1;
    float s = 0.f;
#pragma unroll
    for (int w8=0; w8<8; w8++) s += sred[g][w8][sel];
    int nn = blockIdx.x*8 + g;
    if (sel) a_dst2[nn] = s; else a_src2[nn] = s;
  }
}

// ---------------- conv2 GEMM: MFMA bf16, BM=80 BN=256 BK=64 (epilogue = pure h2b store) ----------------
__global__ __launch_bounds__(256) void k_gemm2m(const ushort* __restrict__ A,
    const ushort* __restrict__ BT, ushort* __restrict__ h2b){
  __shared__ __align__(16) ushort S[2][(BMG+256)*64];  // [buf][A:5120 | B:16384] elems
  int tid = threadIdx.x;
  int m0 = blockIdx.x*BMG;
  int w = tid>>6, l = tid&63;
  int lrow = l&15, lk = l>>4;
  int nc = w<<6;

  const ushort* gp[11];
#pragma unroll
  for (int rep=0;rep<11;rep++){
    int lin = rep*256 + tid;
    if (lin < BMG*8){                  // A region: row r, slot s
      int r = lin>>3, s = lin&7;
      gp[rep] = A + (size_t)(m0+r)*F1 + ((s ^ (r&7))<<3);
    } else if (lin < (BMG+256)*8){     // B region: col c, slot s
      int j = lin - BMG*8;
      int c = j>>3, s = j&7;
      gp[rep] = BT + (size_t)c*F1 + ((s ^ (c&7))<<3);
    } else gp[rep] = BT;               // unused (rep 10, tid>=128)
  }

  f32x4 acc[5][4] = {};

#pragma unroll
  for (int rep=0;rep<10;rep++) gload16(gp[rep], &S[0][(rep*256+tid)<<3]);
  if (tid < 128) gload16(gp[10], &S[0][(10*256+tid)<<3]);
  __syncthreads();

  int cur = 0;
  for (int t=0; t<GBKS; t++){
    if (t+1 < GBKS){
      int k0 = (t+1)<<6;
#pragma unroll
      for (int rep=0;rep<10;rep++) gload16(gp[rep]+k0, &S[cur^1][(rep*256+tid)<<3]);
      if (tid < 128) gload16(gp[10]+k0, &S[cur^1][(10*256+tid)<<3]);
    }
    const ushort* as_ = &S[cur][0];
    const ushort* bs_ = &S[cur][BMG*64];
#pragma unroll
    for (int kk=0;kk<2;kk++){
      short8 af[5], bfr[4];
#pragma unroll
      for (int m=0;m<5;m++){
        int r = (m<<4) + lrow;
        af[m] = *(const short8*)&as_[(r<<6) + ((((kk<<2)|lk) ^ (r&7))<<3)];
      }
#pragma unroll
      for (int n=0;n<4;n++){
        int c = nc + (n<<4) + lrow;
        bfr[n] = *(const short8*)&bs_[(c<<6) + ((((kk<<2)|lk) ^ (c&7))<<3)];
      }
#pragma unroll
      for (int m=0;m<5;m++)
#pragma unroll
        for (int n=0;n<4;n++)
          acc[m][n] = __builtin_amdgcn_mfma_f32_16x16x32_bf16(af[m], bfr[n], acc[m][n], 0,0,0);
    }
    __syncthreads();
    cur ^= 1;
  }

  // epilogue: bf16 h2 store only (attention dots moved to k_sa1 via ws2/wd2 factorization)
#pragma unroll
  for (int m=0;m<5;m++){
#pragma unroll
    for (int j=0;j<4;j++){
      int grow = m0 + (m<<4) + (lk<<2) + j;
#pragma unroll
      for (int n=0;n<4;n++)
        h2b[(size_t)grow*256 + nc+(n<<4)+lrow] = f2bf(acc[m][n][j]);
    }
  }
}

// ---------------- conv2 aggregation → output: wave per node, 8/block, max-free softmax ----------------
__global__ __launch_bounds__(512) void k_agg2(const int* __restrict__ cnt, const int* __restrict__ bucket,
    const float* __restrict__ a_src2, const float* __restrict__ a_dst2, const ushort* __restrict__ h2b,
    const float* __restrict__ b2, float* __restrict__ out){
  int tid = threadIdx.x, wv = tid>>6, lane = tid&63;
  int n = blockIdx.x*8 + wv;
  int base = n*MAXDEG;
  int deg  = cnt[n]; if (deg > MAXDEG) deg = MAXDEG;
  float ad = a_dst2[n];

  int src0 = (lane<deg)     ? bucket[base+lane]    : 0;
  int src1 = (lane+64<deg)  ? bucket[base+lane+64] : 0;
  float e0 = 0.f, e1 = 0.f;
  if (lane<deg)   { float a = a_src2[src0]+ad; a = (a>0.f)?a:NEG*a; e0 = __expf(a); }
  if (lane+64<deg){ float a = a_src2[src1]+ad; a = (a>0.f)?a:NEG*a; e1 = __expf(a); }
  float s = e0+e1;
  for (int off=32; off; off>>=1) s += __shfl_xor(s,off);
  float inv = 1.f/(s+1e-16f);
  e0 *= inv; e1 *= inv;

  int c0 = lane<<2;
  float acc0=0.f, acc1=0.f, acc2=0.f, acc3=0.f;
  int d1 = (deg<64)?deg:64;
  for (int j=0;j<d1;j++){
    float w = __shfl(e0, j);
    int  sj = __shfl(src0, j);
    short4_ hv = *(const short4_*)(h2b + (size_t)sj*256 + c0);
    acc0 += w*bf2f((ushort)hv[0]); acc1 += w*bf2f((ushort)hv[1]);
    acc2 += w*bf2f((ushort)hv[2]); acc3 += w*bf2f((ushort)hv[3]);
  }
  for (int j=64;j<deg;j++){
    float w = __shfl(e1, j-64);
    int  sj = __shfl(src1, j-64);
    short4_ hv = *(const short4_*)(h2b + (size_t)sj*256 + c0);
    acc0 += w*bf2f((ushort)hv[0]); acc1 += w*bf2f((ushort)hv[1]);
    acc2 += w*bf2f((ushort)hv[2]); acc3 += w*bf2f((ushort)hv[3]);
  }
  f32x4 bb = *(const f32x4*)(b2 + c0);
  f32x4 o; o[0]=acc0+bb[0]; o[1]=acc1+bb[1]; o[2]=acc2+bb[2]; o[3]=acc3+bb[3];
  *(f32x4*)(out + (size_t)n*256 + c0) = o;
}

extern "C" void kernel_launch(void* const* d_in, const int* in_sizes, int n_in,
                              void* d_out, int out_size, void* d_ws, size_t ws_size,
                              hipStream_t stream){
  const float* x      = (const float*)d_in[0];
  const int*   ei     = (const int*)  d_in[1];
  const float* W1     = (const float*)d_in[2];
  const float* att_s1 = (const float*)d_in[3];
  const float* att_d1 = (const float*)d_in[4];
  const float* b1     = (const float*)d_in[5];
  const float* W2     = (const float*)d_in[6];
  const float* att_s2 = (const float*)d_in[7];
  const float* att_d2 = (const float*)d_in[8];
  const float* b2     = (const float*)d_in[9];
  float* out = (float*)d_out;

  char* p = (char*)d_ws;
  auto alloc = [&](size_t bytes)->char*{ char* r = p; p += (bytes + 255) & ~(size_t)255; return r; };
  ushort* x2    = (ushort*)alloc((size_t)N_NODES*F1*2);
  ushort* W2bT  = (ushort*)alloc((size_t)F1*256*2);
  ushort* h2b   = (ushort*)alloc((size_t)N_NODES*256*2);
  float*  a_src1= (float*) alloc((size_t)N_NODES*8*4);
  float*  a_dst1= (float*) alloc((size_t)N_NODES*8*4);
  float*  a_src2= (float*) alloc((size_t)N_NODES*4);
  float*  a_dst2= (float*) alloc((size_t)N_NODES*4);
  float*  ws2   = (float*) alloc((size_t)F1*4);
  float*  wd2   = (float*) alloc((size_t)F1*4);
  int*    cnt   = (int*)   alloc((size_t)N_NODES*4);
  int*    bucket= (int*)   alloc((size_t)N_NODES*MAXDEG*4);

  k_pre    <<<(N_NODES+31)/32, 256, 0, stream>>>(x, W1, att_s1, att_d1, W2, att_s2, att_d2,
                                                 a_src1, a_dst1, W2bT, ws2, wd2, cnt);
  k_scat   <<<(E_TOT+255)/256, 256, 0, stream>>>(ei, cnt, bucket);
  k_sa1    <<<N_NODES/8, 512, 0, stream>>>(cnt, bucket, a_src1, a_dst1, x, W1, b1,
                                           ws2, wd2, x2, a_src2, a_dst2);
  k_gemm2m <<<N_NODES/BMG, 256, 0, stream>>>(x2, W2bT, h2b);
  k_agg2   <<<N_NODES/8, 512, 0, stream>>>(cnt, bucket, a_src2, a_dst2, h2b, b2, out);
}

// Round 20
// 118.456 us; speedup vs baseline: 1.0658x; 1.0658x over previous
//
#include <hip/hip_runtime.h>
#include <hip/hip_bf16.h>

#define N_NODES 20000
#define E_ORIG  160000
#define E_TOT   180000
#define HEADS   8
#define HID     256
#define F1      2048   // HEADS*HID
#define NEG     0.2f
#define MAXDEG  96
#define GBKS    32     // K steps for gemm2: 2048/64
#define BMG     80     // gemm2 M-tile: 20000/80 = 250 blocks = 1/CU exact

typedef __attribute__((ext_vector_type(8))) short  short8;
typedef __attribute__((ext_vector_type(4))) short  short4_;
typedef __attribute__((ext_vector_type(4))) float  f32x4;

__device__ inline float bf2f(ushort u){ union{unsigned u32; float f;} v; v.u32=((unsigned)u)<<16; return v.f; }
__device__ inline ushort f2bf(float f){
  union{float f; unsigned u;} v; v.f=f;
  unsigned lsb=(v.u>>16)&1u; v.u += 0x7fffu + lsb; return (ushort)(v.u>>16);
}

__device__ inline void gload16(const ushort* g, ushort* s){
  __builtin_amdgcn_global_load_lds((const __attribute__((address_space(1))) unsigned int*)g,
                                   (__attribute__((address_space(3))) unsigned int*)s, 16, 0, 0);
}

// ---------------- fused prelude: prep + dots1 + cnt-zero + W2 transpose ----------------
__global__ __launch_bounds__(256) void k_pre(const float* __restrict__ x, const float* __restrict__ W1,
    const float* __restrict__ as1, const float* __restrict__ ad1, const float* __restrict__ W2,
    float* __restrict__ a_src1, float* __restrict__ a_dst1, ushort* __restrict__ W2bT,
    int* __restrict__ cnt){
  __shared__ float s_w[128];
  __shared__ ushort sh[256][65];
  int tid = threadIdx.x, bid = blockIdx.x;
  if (tid < 128){
    int t = tid & 63;
    int k = t>>3, i = t&7;
    float v = 0.f;
    if (i < 7){
      const float* wp = W1 + i*F1 + (k<<8);
      const float* ap = ((tid<64) ? as1 : ad1) + (k<<8);
      f32x4 a4 = {0,0,0,0};
      for (int c=0;c<256;c+=4)
        a4 += (*(const f32x4*)&wp[c]) * (*(const f32x4*)&ap[c]);
      v = a4[0]+a4[1]+a4[2]+a4[3];
    }
    s_w[tid] = v;
  }
  __syncthreads();
  {
    int nl = tid>>3, k = tid&7;
    int n = bid*32 + nl;
    if (n < N_NODES){
      float s=0.f, d=0.f;
      const float* ws = &s_w[k*8];
      const float* wd = &s_w[64+k*8];
#pragma unroll
      for (int i=0;i<7;i++){
        float xv = x[n*7+i];
        s += xv*ws[i]; d += xv*wd[i];
      }
      a_src1[n*8+k]=s; a_dst1[n*8+k]=d;
    }
  }
  if (bid >= 32 && bid < 111){
    int i = (bid-32)*256 + tid;
    if (i < N_NODES) cnt[i] = 0;
  }
  if (bid < 32){
    int k0 = bid*64;
    for (int kk=0; kk<64; kk++) sh[tid][kk] = f2bf(W2[(size_t)(k0+kk)*256 + tid]);
    __syncthreads();
#pragma unroll
    for (int c8=0; c8<8; c8++){
      short8 v;
#pragma unroll
      for (int j=0;j<8;j++) v[j] = (short)sh[tid][c8*8+j];
      *(short8*)&W2bT[(size_t)tid*F1 + k0 + c8*8] = v;
    }
  }
}

// ---------------- bucketed scatter ----------------
__global__ void k_scat(const int* __restrict__ ei, int* __restrict__ cnt, int* __restrict__ bucket){
  int e = blockIdx.x*256 + threadIdx.x;
  if (e >= E_TOT) return;
  int s, d;
  if (e < E_ORIG){ s = ei[e]; d = ei[E_ORIG + e]; }
  else           { s = d = e - E_ORIG; }
  int pos = atomicAdd(&cnt[d], 1);
  if (pos < MAXDEG) bucket[d*MAXDEG + pos] = s;
}

// ---------------- fused conv1: softmax+agg (wave/node, x4-unrolled MLP) -> W1 apply + ELU -> x2 ----------------
__global__ __launch_bounds__(512) void k_sa1(const int* __restrict__ cnt, const int* __restrict__ bucket,
    const float* __restrict__ a_src1, const float* __restrict__ a_dst1,
    const float* __restrict__ x, const float* __restrict__ W1, const float* __restrict__ b1,
    ushort* __restrict__ x2){
  __shared__ float sxa[8][64];
  int tid = threadIdx.x, wv = tid>>6, lane = tid&63;
  int n = blockIdx.x*8 + wv;
  {
    int k = lane>>3, i = lane&7;
    int ie = (i==7)?0:i;
    int base = n*MAXDEG;
    int deg  = cnt[n]; if (deg>MAXDEG) deg=MAXDEG;
    float ad = a_dst1[n*8+k];
    int src0 = (lane<deg)    ? bucket[base+lane]    : 0;
    int src1 = (lane+64<deg) ? bucket[base+lane+64] : 0;
    float denom = 0.f, acc = 0.f;
    int j = 0;
    // x4 unroll: 8 independent gathers in flight per step (MLP; indices known upfront)
    for (; j+4<=deg; j+=4){
      int s0 = (j<64)   ? __shfl(src0,j)   : __shfl(src1,j-64);
      int s1 = (j+1<64) ? __shfl(src0,j+1) : __shfl(src1,j-63);
      int s2 = (j+2<64) ? __shfl(src0,j+2) : __shfl(src1,j-62);
      int s3 = (j+3<64) ? __shfl(src0,j+3) : __shfl(src1,j-61);
      float A0 = a_src1[(size_t)s0*8+k];
      float A1 = a_src1[(size_t)s1*8+k];
      float A2 = a_src1[(size_t)s2*8+k];
      float A3 = a_src1[(size_t)s3*8+k];
      float X0 = x[(size_t)s0*7+ie];
      float X1 = x[(size_t)s1*7+ie];
      float X2 = x[(size_t)s2*7+ie];
      float X3 = x[(size_t)s3*7+ie];
      A0 += ad; A1 += ad; A2 += ad; A3 += ad;
      A0 = (A0>0.f)?A0:NEG*A0;  A1 = (A1>0.f)?A1:NEG*A1;
      A2 = (A2>0.f)?A2:NEG*A2;  A3 = (A3>0.f)?A3:NEG*A3;
      float w0 = __expf(A0), w1 = __expf(A1), w2 = __expf(A2), w3 = __expf(A3);
      denom += w0; acc += w0*X0;
      denom += w1; acc += w1*X1;
      denom += w2; acc += w2*X2;
      denom += w3; acc += w3*X3;
    }
    for (; j<deg; j++){
      int s0 = (j<64) ? __shfl(src0,j) : __shfl(src1,j-64);
      float A0 = a_src1[(size_t)s0*8+k] + ad;
      A0 = (A0>0.f)?A0:NEG*A0;
      float w0 = __expf(A0);
      denom += w0; acc += w0*x[(size_t)s0*7+ie];
    }
    sxa[wv][lane] = acc/denom;
  }
  __syncthreads();
  // phase 2: apply W1
  int kh = tid>>6, c4 = (tid&63)<<2;
  f32x4 w1r[7];
#pragma unroll
  for (int i=0;i<7;i++) w1r[i] = *(const f32x4*)(W1 + i*F1 + (kh<<8) + c4);
  f32x4 bb = *(const f32x4*)(b1 + (kh<<8) + c4);
#pragma unroll
  for (int g=0; g<8; g++){
    int nn = blockIdx.x*8 + g;
    const float* xa = &sxa[g][kh<<3];
    f32x4 h = bb;
#pragma unroll
    for (int i=0;i<7;i++) h += xa[i]*w1r[i];
    short4_ o;
#pragma unroll
    for (int j=0;j<4;j++){ float v=h[j]; v=(v>0.f)?v:(__expf(v)-1.f); o[j]=(short)f2bf(v); }
    *(short4_*)(x2 + (size_t)nn*F1 + (kh<<8) + c4) = o;
  }
}

// ---------------- conv2 GEMM: MFMA bf16, BM=80 BN=256 BK=64, 4 waves (80x64 wave tiles) ----------------
__global__ __launch_bounds__(256) void k_gemm2m(const ushort* __restrict__ A,
    const ushort* __restrict__ BT, ushort* __restrict__ h2b,
    const float* __restrict__ as2, const float* __restrict__ ad2,
    float* __restrict__ a_src2, float* __restrict__ a_dst2){
  __shared__ __align__(16) ushort S[2][(BMG+256)*64];  // [buf][A:5120 | B:16384] elems
  int tid = threadIdx.x;
  int m0 = blockIdx.x*BMG;
  int w = tid>>6, l = tid&63;
  int lrow = l&15, lk = l>>4;
  int nc = w<<6;

  const ushort* gp[11];
#pragma unroll
  for (int rep=0;rep<11;rep++){
    int lin = rep*256 + tid;
    if (lin < BMG*8){                  // A region: row r, slot s
      int r = lin>>3, s = lin&7;
      gp[rep] = A + (size_t)(m0+r)*F1 + ((s ^ (r&7))<<3);
    } else if (lin < (BMG+256)*8){     // B region: col c, slot s
      int j = lin - BMG*8;
      int c = j>>3, s = j&7;
      gp[rep] = BT + (size_t)c*F1 + ((s ^ (c&7))<<3);
    } else gp[rep] = BT;               // unused (rep 10, tid>=128)
  }

  f32x4 acc[5][4] = {};

#pragma unroll
  for (int rep=0;rep<10;rep++) gload16(gp[rep], &S[0][(rep*256+tid)<<3]);
  if (tid < 128) gload16(gp[10], &S[0][(10*256+tid)<<3]);
  __syncthreads();

  int cur = 0;
  for (int t=0; t<GBKS; t++){
    if (t+1 < GBKS){
      int k0 = (t+1)<<6;
#pragma unroll
      for (int rep=0;rep<10;rep++) gload16(gp[rep]+k0, &S[cur^1][(rep*256+tid)<<3]);
      if (tid < 128) gload16(gp[10]+k0, &S[cur^1][(10*256+tid)<<3]);
    }
    const ushort* as_ = &S[cur][0];
    const ushort* bs_ = &S[cur][BMG*64];
#pragma unroll
    for (int kk=0;kk<2;kk++){
      short8 af[5], bfr[4];
#pragma unroll
      for (int m=0;m<5;m++){
        int r = (m<<4) + lrow;
        af[m] = *(const short8*)&as_[(r<<6) + ((((kk<<2)|lk) ^ (r&7))<<3)];
      }
#pragma unroll
      for (int n=0;n<4;n++){
        int c = nc + (n<<4) + lrow;
        bfr[n] = *(const short8*)&bs_[(c<<6) + ((((kk<<2)|lk) ^ (c&7))<<3)];
      }
#pragma unroll
      for (int m=0;m<5;m++)
#pragma unroll
        for (int n=0;n<4;n++)
          acc[m][n] = __builtin_amdgcn_mfma_f32_16x16x32_bf16(af[m], bfr[n], acc[m][n], 0,0,0);
    }
    __syncthreads();
    cur ^= 1;
  }

  // epilogue: bf16 h2 store + attention-dot cross-wave LDS reduce
  float* sps = (float*)&S[0][0];       // [80 rows][4 waves]
  float* spd = sps + BMG*4;
  float s2v[4], d2v[4];
#pragma unroll
  for (int n=0;n<4;n++){
    int col = nc + (n<<4) + lrow;
    s2v[n]=as2[col]; d2v[n]=ad2[col];
  }
#pragma unroll
  for (int m=0;m<5;m++){
#pragma unroll
    for (int j=0;j<4;j++){
      int lr = (m<<4) + (lk<<2) + j;
      int grow = m0 + lr;
      float ps=0.f, pd=0.f;
#pragma unroll
      for (int n=0;n<4;n++){
        float v = acc[m][n][j];
        ps += v*s2v[n]; pd += v*d2v[n];
        h2b[(size_t)grow*256 + nc+(n<<4)+lrow] = f2bf(v);
      }
      ps += __shfl_xor(ps,8); ps += __shfl_xor(ps,4); ps += __shfl_xor(ps,2); ps += __shfl_xor(ps,1);
      pd += __shfl_xor(pd,8); pd += __shfl_xor(pd,4); pd += __shfl_xor(pd,2); pd += __shfl_xor(pd,1);
      if (lrow==0){
        sps[(lr<<2) | w] = ps;
        spd[(lr<<2) | w] = pd;
      }
    }
  }
  __syncthreads();
  if (tid < BMG){
    int grow = m0 + tid;
    f32x4 a = *(const f32x4*)&sps[tid<<2];
    f32x4 b = *(const f32x4*)&spd[tid<<2];
    a_src2[grow] = a[0]+a[1]+a[2]+a[3];
    a_dst2[grow] = b[0]+b[1]+b[2]+b[3];
  }
}

// ---------------- conv2 aggregation → output: wave per node, 8/block, max-free softmax ----------------
__global__ __launch_bounds__(512) void k_agg2(const int* __restrict__ cnt, const int* __restrict__ bucket,
    const float* __restrict__ a_src2, const float* __restrict__ a_dst2, const ushort* __restrict__ h2b,
    const float* __restrict__ b2, float* __restrict__ out){
  int tid = threadIdx.x, wv = tid>>6, lane = tid&63;
  int n = blockIdx.x*8 + wv;
  int base = n*MAXDEG;
  int deg  = cnt[n]; if (deg > MAXDEG) deg = MAXDEG;
  float ad = a_dst2[n];

  int src0 = (lane<deg)     ? bucket[base+lane]    : 0;
  int src1 = (lane+64<deg)  ? bucket[base+lane+64] : 0;
  float e0 = 0.f, e1 = 0.f;
  if (lane<deg)   { float a = a_src2[src0]+ad; a = (a>0.f)?a:NEG*a; e0 = __expf(a); }
  if (lane+64<deg){ float a = a_src2[src1]+ad; a = (a>0.f)?a:NEG*a; e1 = __expf(a); }
  float s = e0+e1;
  for (int off=32; off; off>>=1) s += __shfl_xor(s,off);
  float inv = 1.f/(s+1e-16f);
  e0 *= inv; e1 *= inv;

  int c0 = lane<<2;
  float acc0=0.f, acc1=0.f, acc2=0.f, acc3=0.f;
  int d1 = (deg<64)?deg:64;
  for (int j=0;j<d1;j++){
    float w = __shfl(e0, j);
    int  sj = __shfl(src0, j);
    short4_ hv = *(const short4_*)(h2b + (size_t)sj*256 + c0);
    acc0 += w*bf2f((ushort)hv[0]); acc1 += w*bf2f((ushort)hv[1]);
    acc2 += w*bf2f((ushort)hv[2]); acc3 += w*bf2f((ushort)hv[3]);
  }
  for (int j=64;j<deg;j++){
    float w = __shfl(e1, j-64);
    int  sj = __shfl(src1, j-64);
    short4_ hv = *(const short4_*)(h2b + (size_t)sj*256 + c0);
    acc0 += w*bf2f((ushort)hv[0]); acc1 += w*bf2f((ushort)hv[1]);
    acc2 += w*bf2f((ushort)hv[2]); acc3 += w*bf2f((ushort)hv[3]);
  }
  f32x4 bb = *(const f32x4*)(b2 + c0);
  f32x4 o; o[0]=acc0+bb[0]; o[1]=acc1+bb[1]; o[2]=acc2+bb[2]; o[3]=acc3+bb[3];
  *(f32x4*)(out + (size_t)n*256 + c0) = o;
}

extern "C" void kernel_launch(void* const* d_in, const int* in_sizes, int n_in,
                              void* d_out, int out_size, void* d_ws, size_t ws_size,
                              hipStream_t stream){
  const float* x      = (const float*)d_in[0];
  const int*   ei     = (const int*)  d_in[1];
  const float* W1     = (const float*)d_in[2];
  const float* att_s1 = (const float*)d_in[3];
  const float* att_d1 = (const float*)d_in[4];
  const float* b1     = (const float*)d_in[5];
  const float* W2     = (const float*)d_in[6];
  const float* att_s2 = (const float*)d_in[7];
  const float* att_d2 = (const float*)d_in[8];
  const float* b2     = (const float*)d_in[9];
  float* out = (float*)d_out;

  char* p = (char*)d_ws;
  auto alloc = [&](size_t bytes)->char*{ char* r = p; p += (bytes + 255) & ~(size_t)255; return r; };
  ushort* x2    = (ushort*)alloc((size_t)N_NODES*F1*2);
  ushort* W2bT  = (ushort*)alloc((size_t)F1*256*2);
  ushort* h2b   = (ushort*)alloc((size_t)N_NODES*256*2);
  float*  a_src1= (float*) alloc((size_t)N_NODES*8*4);
  float*  a_dst1= (float*) alloc((size_t)N_NODES*8*4);
  float*  a_src2= (float*) alloc((size_t)N_NODES*4);
  float*  a_dst2= (float*) alloc((size_t)N_NODES*4);
  int*    cnt   = (int*)   alloc((size_t)N_NODES*4);
  int*    bucket= (int*)   alloc((size_t)N_NODES*MAXDEG*4);

  k_pre    <<<(N_NODES+31)/32, 256, 0, stream>>>(x, W1, att_s1, att_d1, W2,
                                                 a_src1, a_dst1, W2bT, cnt);
  k_scat   <<<(E_TOT+255)/256, 256, 0, stream>>>(ei, cnt, bucket);
  k_sa1    <<<N_NODES/8, 512, 0, stream>>>(cnt, bucket, a_src1, a_dst1, x, W1, b1, x2);
  k_gemm2m <<<N_NODES/BMG, 256, 0, stream>>>(x2, W2bT, h2b, att_s2, att_d2, a_src2, a_dst2);
  k_agg2   <<<N_NODES/8, 512, 0, stream>>>(cnt, bucket, a_src2, a_dst2, h2b, b2, out);
}

// Round 21
// 117.177 us; speedup vs baseline: 1.0775x; 1.0109x over previous
//
#include <hip/hip_runtime.h>
#include <hip/hip_bf16.h>

#define N_NODES 20000
#define E_ORIG  160000
#define E_TOT   180000
#define HEADS   8
#define HID     256
#define F1      2048   // HEADS*HID
#define NEG     0.2f
#define MAXDEG  96
#define GBKS    32     // K steps for gemm2: 2048/64
#define BMG     80     // gemm2 M-tile: 20000/80 = 250 blocks = 1/CU exact

typedef __attribute__((ext_vector_type(8))) short  short8;
typedef __attribute__((ext_vector_type(4))) short  short4_;
typedef __attribute__((ext_vector_type(4))) float  f32x4;

__device__ inline float bf2f(ushort u){ union{unsigned u32; float f;} v; v.u32=((unsigned)u)<<16; return v.f; }
__device__ inline ushort f2bf(float f){
  union{float f; unsigned u;} v; v.f=f;
  unsigned lsb=(v.u>>16)&1u; v.u += 0x7fffu + lsb; return (ushort)(v.u>>16);
}

__device__ inline void gload16(const ushort* g, ushort* s){
  __builtin_amdgcn_global_load_lds((const __attribute__((address_space(1))) unsigned int*)g,
                                   (__attribute__((address_space(3))) unsigned int*)s, 16, 0, 0);
}

// ---------------- fused prelude: prep + dots1 + cnt-zero + W2 transpose ----------------
__global__ __launch_bounds__(256) void k_pre(const float* __restrict__ x, const float* __restrict__ W1,
    const float* __restrict__ as1, const float* __restrict__ ad1, const float* __restrict__ W2,
    float* __restrict__ a_src1, float* __restrict__ a_dst1, ushort* __restrict__ W2bT,
    int* __restrict__ cnt){
  __shared__ float s_w[128];
  __shared__ ushort sh[256][65];
  int tid = threadIdx.x, bid = blockIdx.x;
  if (tid < 128){
    int t = tid & 63;
    int k = t>>3, i = t&7;
    float v = 0.f;
    if (i < 7){
      const float* wp = W1 + i*F1 + (k<<8);
      const float* ap = ((tid<64) ? as1 : ad1) + (k<<8);
      f32x4 a4 = {0,0,0,0};
      for (int c=0;c<256;c+=4)
        a4 += (*(const f32x4*)&wp[c]) * (*(const f32x4*)&ap[c]);
      v = a4[0]+a4[1]+a4[2]+a4[3];
    }
    s_w[tid] = v;
  }
  __syncthreads();
  {
    int nl = tid>>3, k = tid&7;
    int n = bid*32 + nl;
    if (n < N_NODES){
      float s=0.f, d=0.f;
      const float* ws = &s_w[k*8];
      const float* wd = &s_w[64+k*8];
#pragma unroll
      for (int i=0;i<7;i++){
        float xv = x[n*7+i];
        s += xv*ws[i]; d += xv*wd[i];
      }
      a_src1[n*8+k]=s; a_dst1[n*8+k]=d;
    }
  }
  if (bid >= 32 && bid < 111){
    int i = (bid-32)*256 + tid;
    if (i < N_NODES) cnt[i] = 0;
  }
  if (bid < 32){
    int k0 = bid*64;
    for (int kk=0; kk<64; kk++) sh[tid][kk] = f2bf(W2[(size_t)(k0+kk)*256 + tid]);
    __syncthreads();
#pragma unroll
    for (int c8=0; c8<8; c8++){
      short8 v;
#pragma unroll
      for (int j=0;j<8;j++) v[j] = (short)sh[tid][c8*8+j];
      *(short8*)&W2bT[(size_t)tid*F1 + k0 + c8*8] = v;
    }
  }
}

// ---------------- bucketed scatter ----------------
__global__ void k_scat(const int* __restrict__ ei, int* __restrict__ cnt, int* __restrict__ bucket){
  int e = blockIdx.x*256 + threadIdx.x;
  if (e >= E_TOT) return;
  int s, d;
  if (e < E_ORIG){ s = ei[e]; d = ei[E_ORIG + e]; }
  else           { s = d = e - E_ORIG; }
  int pos = atomicAdd(&cnt[d], 1);
  if (pos < MAXDEG) bucket[d*MAXDEG + pos] = s;
}

// ---------------- fused conv1: softmax+agg (wave/node, x4-unrolled MLP) -> W1 apply + ELU -> x2 ----------------
__global__ __launch_bounds__(512) void k_sa1(const int* __restrict__ cnt, const int* __restrict__ bucket,
    const float* __restrict__ a_src1, const float* __restrict__ a_dst1,
    const float* __restrict__ x, const float* __restrict__ W1, const float* __restrict__ b1,
    ushort* __restrict__ x2){
  __shared__ float sxa[8][64];
  int tid = threadIdx.x, wv = tid>>6, lane = tid&63;
  int n = blockIdx.x*8 + wv;
  {
    int k = lane>>3, i = lane&7;
    int ie = (i==7)?0:i;
    int base = n*MAXDEG;
    int deg  = cnt[n]; if (deg>MAXDEG) deg=MAXDEG;
    float ad = a_dst1[n*8+k];
    int src0 = (lane<deg)    ? bucket[base+lane]    : 0;
    int src1 = (lane+64<deg) ? bucket[base+lane+64] : 0;
    float denom = 0.f, acc = 0.f;
    int j = 0;
    for (; j+4<=deg; j+=4){
      int s0 = (j<64)   ? __shfl(src0,j)   : __shfl(src1,j-64);
      int s1 = (j+1<64) ? __shfl(src0,j+1) : __shfl(src1,j-63);
      int s2 = (j+2<64) ? __shfl(src0,j+2) : __shfl(src1,j-62);
      int s3 = (j+3<64) ? __shfl(src0,j+3) : __shfl(src1,j-61);
      float A0 = a_src1[(size_t)s0*8+k];
      float A1 = a_src1[(size_t)s1*8+k];
      float A2 = a_src1[(size_t)s2*8+k];
      float A3 = a_src1[(size_t)s3*8+k];
      float X0 = x[(size_t)s0*7+ie];
      float X1 = x[(size_t)s1*7+ie];
      float X2 = x[(size_t)s2*7+ie];
      float X3 = x[(size_t)s3*7+ie];
      A0 += ad; A1 += ad; A2 += ad; A3 += ad;
      A0 = (A0>0.f)?A0:NEG*A0;  A1 = (A1>0.f)?A1:NEG*A1;
      A2 = (A2>0.f)?A2:NEG*A2;  A3 = (A3>0.f)?A3:NEG*A3;
      float w0 = __expf(A0), w1 = __expf(A1), w2 = __expf(A2), w3 = __expf(A3);
      denom += w0; acc += w0*X0;
      denom += w1; acc += w1*X1;
      denom += w2; acc += w2*X2;
      denom += w3; acc += w3*X3;
    }
    for (; j<deg; j++){
      int s0 = (j<64) ? __shfl(src0,j) : __shfl(src1,j-64);
      float A0 = a_src1[(size_t)s0*8+k] + ad;
      A0 = (A0>0.f)?A0:NEG*A0;
      float w0 = __expf(A0);
      denom += w0; acc += w0*x[(size_t)s0*7+ie];
    }
    sxa[wv][lane] = acc/denom;
  }
  __syncthreads();
  int kh = tid>>6, c4 = (tid&63)<<2;
  f32x4 w1r[7];
#pragma unroll
  for (int i=0;i<7;i++) w1r[i] = *(const f32x4*)(W1 + i*F1 + (kh<<8) + c4);
  f32x4 bb = *(const f32x4*)(b1 + (kh<<8) + c4);
#pragma unroll
  for (int g=0; g<8; g++){
    int nn = blockIdx.x*8 + g;
    const float* xa = &sxa[g][kh<<3];
    f32x4 h = bb;
#pragma unroll
    for (int i=0;i<7;i++) h += xa[i]*w1r[i];
    short4_ o;
#pragma unroll
    for (int j=0;j<4;j++){ float v=h[j]; v=(v>0.f)?v:(__expf(v)-1.f); o[j]=(short)f2bf(v); }
    *(short4_*)(x2 + (size_t)nn*F1 + (kh<<8) + c4) = o;
  }
}

// ---------------- conv2 GEMM: wave-specialized producer/consumer, BM=80 BN=256 BK=64 ----------------
// 512 thr: waves 0-3 = consumers (ds_read+MFMA only), waves 4-7 = producers (global_load_lds only).
// Raw s_barrier per step; producer drains its OWN vmcnt concurrent with consumer MFMA.
__global__ __launch_bounds__(512) void k_gemm2m(const ushort* __restrict__ A,
    const ushort* __restrict__ BT, ushort* __restrict__ h2b,
    const float* __restrict__ as2, const float* __restrict__ ad2,
    float* __restrict__ a_src2, float* __restrict__ a_dst2){
  __shared__ __align__(16) ushort S[2][(BMG+256)*64];  // 2 x 43008 B
  int tid = threadIdx.x;
  int m0 = blockIdx.x*BMG;
  int w = tid>>6, l = tid&63;
  int lrow = l&15, lk = l>>4;
  int nc = (w&3)<<6;

  f32x4 acc[5][4] = {};

  if (w >= 4){
    // ---------------- producer waves ----------------
    int pt = tid - 256;                 // 0..255
    const ushort* gp[11];
    bool act[11];
#pragma unroll
    for (int rep=0;rep<11;rep++){
      int lin = rep*256 + pt;
      act[rep] = lin < (BMG+256)*8;     // 2688; wave-uniform (rep10: producer waves 0,1 only)
      int linc = act[rep] ? lin : 0;
      if (linc < BMG*8){                // A region: row r, slot s
        int r = linc>>3, s = linc&7;
        gp[rep] = A + (size_t)(m0+r)*F1 + ((s ^ (r&7))<<3);
      } else {                          // B region: col c, slot s
        int j = linc - BMG*8;
        int c = j>>3, s = j&7;
        gp[rep] = BT + (size_t)c*F1 + ((s ^ (c&7))<<3);
      }
    }
    // prologue: stage t=0 into S[0]
#pragma unroll
    for (int rep=0;rep<11;rep++)
      if (act[rep]) gload16(gp[rep], &S[0][(rep*256+pt)<<3]);
    asm volatile("s_waitcnt vmcnt(0)" ::: "memory");
    __builtin_amdgcn_s_barrier();
    __builtin_amdgcn_sched_barrier(0);
    for (int t=0; t<GBKS; t++){
      if (t+1 < GBKS){
        int k0 = (t+1)<<6;
        ushort* dst = &S[(t+1)&1][0];
#pragma unroll
        for (int rep=0;rep<11;rep++)
          if (act[rep]) gload16(gp[rep]+k0, &dst[(rep*256+pt)<<3]);
        asm volatile("s_waitcnt vmcnt(0)" ::: "memory");
      }
      __builtin_amdgcn_s_barrier();
      __builtin_amdgcn_sched_barrier(0);
    }
  } else {
    // ---------------- consumer waves ----------------
    __builtin_amdgcn_s_barrier();       // match prologue
    __builtin_amdgcn_sched_barrier(0);
    for (int t=0; t<GBKS; t++){
      const ushort* as_ = &S[t&1][0];
      const ushort* bs_ = &S[t&1][BMG*64];
#pragma unroll
      for (int kk=0;kk<2;kk++){
        short8 af[5], bfr[4];
#pragma unroll
        for (int m=0;m<5;m++){
          int r = (m<<4) + lrow;
          af[m] = *(const short8*)&as_[(r<<6) + ((((kk<<2)|lk) ^ (r&7))<<3)];
        }
#pragma unroll
        for (int n=0;n<4;n++){
          int c = nc + (n<<4) + lrow;
          bfr[n] = *(const short8*)&bs_[(c<<6) + ((((kk<<2)|lk) ^ (c&7))<<3)];
        }
#pragma unroll
        for (int m=0;m<5;m++)
#pragma unroll
          for (int n=0;n<4;n++)
            acc[m][n] = __builtin_amdgcn_mfma_f32_16x16x32_bf16(af[m], bfr[n], acc[m][n], 0,0,0);
      }
      __builtin_amdgcn_s_barrier();
      __builtin_amdgcn_sched_barrier(0);
    }
  }

  // ---------------- epilogue (all 512 threads; consumer waves hold acc) ----------------
  float* sps = (float*)&S[0][0];       // [80 rows][4 waves]
  float* spd = sps + BMG*4;
  if (w < 4){
    float s2v[4], d2v[4];
#pragma unroll
    for (int n=0;n<4;n++){
      int col = nc + (n<<4) + lrow;
      s2v[n]=as2[col]; d2v[n]=ad2[col];
    }
#pragma unroll
    for (int m=0;m<5;m++){
#pragma unroll
      for (int j=0;j<4;j++){
        int lr = (m<<4) + (lk<<2) + j;
        int grow = m0 + lr;
        float ps=0.f, pd=0.f;
#pragma unroll
        for (int n=0;n<4;n++){
          float v = acc[m][n][j];
          ps += v*s2v[n]; pd += v*d2v[n];
          h2b[(size_t)grow*256 + nc+(n<<4)+lrow] = f2bf(v);
        }
        ps += __shfl_xor(ps,8); ps += __shfl_xor(ps,4); ps += __shfl_xor(ps,2); ps += __shfl_xor(ps,1);
        pd += __shfl_xor(pd,8); pd += __shfl_xor(pd,4); pd += __shfl_xor(pd,2); pd += __shfl_xor(pd,1);
        if (lrow==0){
          sps[(lr<<2) | w] = ps;
          spd[(lr<<2) | w] = pd;
        }
      }
    }
  }
  __syncthreads();
  if (tid < BMG){
    int grow = m0 + tid;
    f32x4 a = *(const f32x4*)&sps[tid<<2];
    f32x4 b = *(const f32x4*)&spd[tid<<2];
    a_src2[grow] = a[0]+a[1]+a[2]+a[3];
    a_dst2[grow] = b[0]+b[1]+b[2]+b[3];
  }
}

// ---------------- conv2 aggregation → output: wave per node, 8/block, max-free softmax ----------------
__global__ __launch_bounds__(512) void k_agg2(const int* __restrict__ cnt, const int* __restrict__ bucket,
    const float* __restrict__ a_src2, const float* __restrict__ a_dst2, const ushort* __restrict__ h2b,
    const float* __restrict__ b2, float* __restrict__ out){
  int tid = threadIdx.x, wv = tid>>6, lane = tid&63;
  int n = blockIdx.x*8 + wv;
  int base = n*MAXDEG;
  int deg  = cnt[n]; if (deg > MAXDEG) deg = MAXDEG;
  float ad = a_dst2[n];

  int src0 = (lane<deg)     ? bucket[base+lane]    : 0;
  int src1 = (lane+64<deg)  ? bucket[base+lane+64] : 0;
  float e0 = 0.f, e1 = 0.f;
  if (lane<deg)   { float a = a_src2[src0]+ad; a = (a>0.f)?a:NEG*a; e0 = __expf(a); }
  if (lane+64<deg){ float a = a_src2[src1]+ad; a = (a>0.f)?a:NEG*a; e1 = __expf(a); }
  float s = e0+e1;
  for (int off=32; off; off>>=1) s += __shfl_xor(s,off);
  float inv = 1.f/(s+1e-16f);
  e0 *= inv; e1 *= inv;

  int c0 = lane<<2;
  float acc0=0.f, acc1=0.f, acc2=0.f, acc3=0.f;
  int d1 = (deg<64)?deg:64;
  for (int j=0;j<d1;j++){
    float w = __shfl(e0, j);
    int  sj = __shfl(src0, j);
    short4_ hv = *(const short4_*)(h2b + (size_t)sj*256 + c0);
    acc0 += w*bf2f((ushort)hv[0]); acc1 += w*bf2f((ushort)hv[1]);
    acc2 += w*bf2f((ushort)hv[2]); acc3 += w*bf2f((ushort)hv[3]);
  }
  for (int j=64;j<deg;j++){
    float w = __shfl(e1, j-64);
    int  sj = __shfl(src1, j-64);
    short4_ hv = *(const short4_*)(h2b + (size_t)sj*256 + c0);
    acc0 += w*bf2f((ushort)hv[0]); acc1 += w*bf2f((ushort)hv[1]);
    acc2 += w*bf2f((ushort)hv[2]); acc3 += w*bf2f((ushort)hv[3]);
  }
  f32x4 bb = *(const f32x4*)(b2 + c0);
  f32x4 o; o[0]=acc0+bb[0]; o[1]=acc1+bb[1]; o[2]=acc2+bb[2]; o[3]=acc3+bb[3];
  *(f32x4*)(out + (size_t)n*256 + c0) = o;
}

extern "C" void kernel_launch(void* const* d_in, const int* in_sizes, int n_in,
                              void* d_out, int out_size, void* d_ws, size_t ws_size,
                              hipStream_t stream){
  const float* x      = (const float*)d_in[0];
  const int*   ei     = (const int*)  d_in[1];
  const float* W1     = (const float*)d_in[2];
  const float* att_s1 = (const float*)d_in[3];
  const float* att_d1 = (const float*)d_in[4];
  const float* b1     = (const float*)d_in[5];
  const float* W2     = (const float*)d_in[6];
  const float* att_s2 = (const float*)d_in[7];
  const float* att_d2 = (const float*)d_in[8];
  const float* b2     = (const float*)d_in[9];
  float* out = (float*)d_out;

  char* p = (char*)d_ws;
  auto alloc = [&](size_t bytes)->char*{ char* r = p; p += (bytes + 255) & ~(size_t)255; return r; };
  ushort* x2    = (ushort*)alloc((size_t)N_NODES*F1*2);
  ushort* W2bT  = (ushort*)alloc((size_t)F1*256*2);
  ushort* h2b   = (ushort*)alloc((size_t)N_NODES*256*2);
  float*  a_src1= (float*) alloc((size_t)N_NODES*8*4);
  float*  a_dst1= (float*) alloc((size_t)N_NODES*8*4);
  float*  a_src2= (float*) alloc((size_t)N_NODES*4);
  float*  a_dst2= (float*) alloc((size_t)N_NODES*4);
  int*    cnt   = (int*)   alloc((size_t)N_NODES*4);
  int*    bucket= (int*)   alloc((size_t)N_NODES*MAXDEG*4);

  k_pre    <<<(N_NODES+31)/32, 256, 0, stream>>>(x, W1, att_s1, att_d1, W2,
                                                 a_src1, a_dst1, W2bT, cnt);
  k_scat   <<<(E_TOT+255)/256, 256, 0, stream>>>(ei, cnt, bucket);
  k_sa1    <<<N_NODES/8, 512, 0, stream>>>(cnt, bucket, a_src1, a_dst1, x, W1, b1, x2);
  k_gemm2m <<<N_NODES/BMG, 512, 0, stream>>>(x2, W2bT, h2b, att_s2, att_d2, a_src2, a_dst2);
  k_agg2   <<<N_NODES/8, 512, 0, stream>>>(cnt, bucket, a_src2, a_dst2, h2b, b2, out);
}